// Round 5
// baseline (267.325 us; speedup 1.0000x reference)
//
#include <hip/hip_runtime.h>
#include <math.h>
#include <stdint.h>
#include <stddef.h>

// Problem dims (fixed by the reference)
#define B_ROWS 4096
#define N_REAL 20000
#define NP2    20224   // N padded to 79*256
#define NJT2   79      // 256-col y tiles
#define D_IN   784
#define DP2    832     // K padded to 13*64
#define NKT    13      // K-tiles of 64
#define NSPLIT2 16     // N-split for flash (grid = 16 x 16 = 256 blocks)
#define LAMBD  0.05f
#define LN2    0.69314718055994530942f

typedef __attribute__((ext_vector_type(8))) short bf16x8;
typedef __attribute__((ext_vector_type(4))) float f32x4;

typedef const unsigned int __attribute__((address_space(1)))* gas_u32p;
typedef unsigned int __attribute__((address_space(3)))* las_u32p;

static __device__ __forceinline__ void gload_lds16(const short* g, short* l) {
  // dest = wave-uniform LDS base + lane*16B; source is per-lane
  __builtin_amdgcn_global_load_lds((gas_u32p)(const void*)g, (las_u32p)(void*)l, 16, 0, 0);
}

static __device__ __forceinline__ float bf2f(short s) {
  union { unsigned u; float f; } c;
  c.u = ((unsigned)(unsigned short)s) << 16;
  return c.f;
}
static __device__ __forceinline__ short f2bf(float f) {
  union { float f; unsigned u; } c;
  c.f = f;
  unsigned r = (c.u + 0x7fffu + ((c.u >> 16) & 1u)) >> 16;  // RNE
  return (short)(unsigned short)r;
}

// ---------------------------------------------------------------------------
// Fused f32->bf16 tiled convert + exact f32 row sum-of-squares.
// dst image per (tile,kt): [kc=8][row=256][8 shorts] (32KB, linear LDS image).
__global__ void k_convfuse(const float* __restrict__ src, short* __restrict__ dst,
                           float* __restrict__ rowsum, int rows_real) {
  __shared__ short img[4096];   // 8 KB quarter image [kc=8][64][8]
  const int tile = blockIdx.x >> 2, quarter = blockIdx.x & 3;
  const int t = threadIdx.x;
  const int q = t & 7, rbase = t >> 3;           // rbase in [0,32)
  float sq0 = 0.f, sq1 = 0.f;

  for (int kt = 0; kt < NKT; ++kt) {
    #pragma unroll
    for (int p = 0; p < 2; ++p) {
      const int rr = rbase + 32 * p;             // [0,64)
      const int grow = tile * 256 + quarter * 64 + rr;
      const int c0 = kt * 64 + q * 8;
      float v[8];
      if (grow < rows_real && c0 < D_IN) {       // D_IN % 8 == 0: chunk all-in or all-out
        const float4* sp = (const float4*)(src + (size_t)grow * D_IN + c0);
        float4 u0 = sp[0], u1 = sp[1];
        v[0] = u0.x; v[1] = u0.y; v[2] = u0.z; v[3] = u0.w;
        v[4] = u1.x; v[5] = u1.y; v[6] = u1.z; v[7] = u1.w;
        float s = v[0]*v[0] + v[1]*v[1] + v[2]*v[2] + v[3]*v[3]
                + v[4]*v[4] + v[5]*v[5] + v[6]*v[6] + v[7]*v[7];
        if (p == 0) sq0 += s; else sq1 += s;
      } else {
        #pragma unroll
        for (int e = 0; e < 8; ++e) v[e] = 0.f;
      }
      bf16x8 o;
      #pragma unroll
      for (int e = 0; e < 8; ++e) o[e] = f2bf(v[e]);
      const int byte = (q * 1024 + rr * 16) ^ (q << 5);   // swizzled LDS write
      *(bf16x8*)((char*)img + byte) = o;
    }
    __syncthreads();
    char* dimgb = (char*)(dst + ((size_t)(tile * NKT + kt) << 14));
    #pragma unroll
    for (int i = 0; i < 2; ++i) {
      const int R = i * 4096 + t * 16;
      const int RS = R ^ (((R >> 10) & 7) << 5);          // unswizzle
      bf16x8 val = *(const bf16x8*)((char*)img + RS);
      const int G = (R >> 10) * 4096 + quarter * 1024 + (R & 1023);
      *(bf16x8*)(dimgb + G) = val;
    }
    __syncthreads();
  }

  #pragma unroll
  for (int m = 1; m < 8; m <<= 1) {
    sq0 += __shfl_xor(sq0, m, 8);
    sq1 += __shfl_xor(sq1, m, 8);
  }
  if (q == 0) {
    const int g0 = tile * 256 + quarter * 64 + rbase;
    if (g0 < rows_real) rowsum[g0] = sq0;
    if (g0 + 32 < rows_real) rowsum[g0 + 32] = sq1;
  }
}

// ---------------------------------------------------------------------------
// All three weight converts in one launch (row-major f32 -> bf16, zero pad).
__global__ void k_convw(const float* __restrict__ W0, const float* __restrict__ W1,
                        const float* __restrict__ W2, short* __restrict__ W0b,
                        short* __restrict__ W1b, short* __restrict__ W2b) {
  const int b = blockIdx.x, t = threadIdx.x;
  const float* src; short* dst; int r, cs, cp;
  if (b < 512)      { r = b;       src = W0; dst = W0b; cs = D_IN; cp = DP2; }
  else if (b < 768) { r = b - 512; src = W1; dst = W1b; cs = 512;  cp = 512; }
  else              { r = b - 768; src = W2; dst = W2b; cs = 256;  cp = 256; }
  const float* sp = src + (size_t)r * cs;
  short* dp = dst + (size_t)r * cp;
  for (int c = t; c < cp; c += 256)
    dp[c] = f2bf(c < cs ? sp[c] : 0.f);
}

// ---------------------------------------------------------------------------
// norm = mean(sy2[0:N_REAL]); scalars: [0]=norm [1]=1/norm [2]=c1
__global__ void k_norm(const float* __restrict__ sy2, float* __restrict__ scal) {
  __shared__ float red[16];
  const int t = threadIdx.x;  // 1024
  float a = 0.f;
  for (int j = t; j < N_REAL; j += 1024) a += sy2[j];
  #pragma unroll
  for (int m = 1; m < 64; m <<= 1) a += __shfl_xor(a, m, 64);
  if ((t & 63) == 0) red[t >> 6] = a;
  __syncthreads();
  if (t == 0) {
    float s = 0.f;
    for (int i = 0; i < 16; ++i) s += red[i];
    float norm = s / (float)N_REAL;
    scal[0] = norm;
    scal[1] = 1.0f / norm;
    scal[2] = 2.0f / (norm * LAMBD * LN2);  // c1: dot -> log2 exponent
  }
}

// ---------------------------------------------------------------------------
// C[M][Ncols](bf16) = act(A * Bm^T + bias). A row-major [M][K] or TILED
// (k_convfuse 256-row image layout). Bm row-major [Ncols][K]. 128x128 tile.
// If psiOut != nullptr (layer-2 mode): psi[row] = sum_col relu(v)*W3[col]+b3.
template <bool TA>
__global__ __launch_bounds__(256) void k_gemm(const short* __restrict__ A,
                                              const short* __restrict__ Bm,
                                              const float* __restrict__ bias,
                                              short* __restrict__ C,
                                              int K, int Ncols, int relu,
                                              const float* __restrict__ W3c,
                                              const float* __restrict__ b3c,
                                              float* __restrict__ psiOut) {
  __shared__ short Als[2][4096];
  __shared__ short Bls[2][4096];
  __shared__ float pbuf[256];
  const int t = threadIdx.x;
  const int lane = t & 63, wave = t >> 6;
  const int lr = lane & 15, lg = lane >> 4;
  const int wrow = (wave >> 1) * 64, wcol = (wave & 1) * 64;
  const int rb = blockIdx.y, cb = blockIdx.x;
  const int srow = t >> 2, skoff = (t & 3) * 8;
  const int KS = K >> 5;

  const short* Ag  = A + (size_t)(rb * 128 + srow) * K + skoff;
  const short* Bg  = Bm + (size_t)(cb * 128 + srow) * K + skoff;
  const size_t halfA = (size_t)64 * K;

  auto a_chunk = [&](int ks, int h) -> const short* {
    if constexpr (TA) {
      return A + ((size_t)((rb >> 1) * NKT + (ks >> 1)) << 14)
               + ((size_t)((((ks & 1) * 4 + (t & 3)) << 8) + (rb & 1) * 128 + h * 64 + srow) << 3);
    } else {
      return Ag + ks * 32 + (h ? halfA : 0);
    }
  };

  f32x4 acc[4][4];
  #pragma unroll
  for (int mi = 0; mi < 4; ++mi)
    #pragma unroll
    for (int ni = 0; ni < 4; ++ni)
      acc[mi][ni] = (f32x4){0.f, 0.f, 0.f, 0.f};

  *(bf16x8*)&Als[0][t * 8]        = *(const bf16x8*)a_chunk(0, 0);
  *(bf16x8*)&Als[0][2048 + t * 8] = *(const bf16x8*)a_chunk(0, 1);
  *(bf16x8*)&Bls[0][t * 8]        = *(const bf16x8*)(Bg);
  *(bf16x8*)&Bls[0][2048 + t * 8] = *(const bf16x8*)(Bg + halfA);
  __syncthreads();

  int cur = 0;
  for (int ks = 0; ks < KS; ++ks) {
    bf16x8 va0, va1, vb0, vb1;
    const bool more = (ks + 1 < KS);
    if (more) {
      va0 = *(const bf16x8*)a_chunk(ks + 1, 0);
      va1 = *(const bf16x8*)a_chunk(ks + 1, 1);
      const short* Bn = Bg + (ks + 1) * 32;
      vb0 = *(const bf16x8*)(Bn);
      vb1 = *(const bf16x8*)(Bn + halfA);
    }
    bf16x8 af[4], bfr[4];
    #pragma unroll
    for (int mi = 0; mi < 4; ++mi)
      af[mi] = *(const bf16x8*)&Als[cur][(wrow + mi * 16 + lr) * 32 + lg * 8];
    #pragma unroll
    for (int ni = 0; ni < 4; ++ni)
      bfr[ni] = *(const bf16x8*)&Bls[cur][(wcol + ni * 16 + lr) * 32 + lg * 8];
    #pragma unroll
    for (int mi = 0; mi < 4; ++mi)
      #pragma unroll
      for (int ni = 0; ni < 4; ++ni)
        acc[mi][ni] = __builtin_amdgcn_mfma_f32_16x16x32_bf16(af[mi], bfr[ni], acc[mi][ni], 0, 0, 0);
    if (more) {
      const int nb = cur ^ 1;
      *(bf16x8*)&Als[nb][t * 8]        = va0;
      *(bf16x8*)&Als[nb][2048 + t * 8] = va1;
      *(bf16x8*)&Bls[nb][t * 8]        = vb0;
      *(bf16x8*)&Bls[nb][2048 + t * 8] = vb1;
    }
    __syncthreads();
    cur ^= 1;
  }

  if (psiOut == nullptr) {
    #pragma unroll
    for (int ni = 0; ni < 4; ++ni) {
      const int col = cb * 128 + wcol + ni * 16 + lr;
      const float bv = bias[col];
      #pragma unroll
      for (int mi = 0; mi < 4; ++mi) {
        const int row0 = rb * 128 + wrow + mi * 16 + lg * 4;
        #pragma unroll
        for (int r = 0; r < 4; ++r) {
          float v = acc[mi][ni][r] + bv;
          if (relu) v = fmaxf(v, 0.f);
          C[(size_t)(row0 + r) * Ncols + col] = f2bf(v);
        }
      }
    }
  } else {
    float part[4][4];
    #pragma unroll
    for (int mi = 0; mi < 4; ++mi)
      #pragma unroll
      for (int r = 0; r < 4; ++r) part[mi][r] = 0.f;
    #pragma unroll
    for (int ni = 0; ni < 4; ++ni) {
      const int col = wcol + ni * 16 + lr;
      const float bv = bias[col];
      const float w3 = W3c[col];
      #pragma unroll
      for (int mi = 0; mi < 4; ++mi)
        #pragma unroll
        for (int r = 0; r < 4; ++r)
          part[mi][r] += fmaxf(acc[mi][ni][r] + bv, 0.f) * w3;
    }
    #pragma unroll
    for (int mi = 0; mi < 4; ++mi)
      #pragma unroll
      for (int r = 0; r < 4; ++r) {
        float s = part[mi][r];
        s += __shfl_xor(s, 1, 16);
        s += __shfl_xor(s, 2, 16);
        s += __shfl_xor(s, 4, 16);
        s += __shfl_xor(s, 8, 16);
        part[mi][r] = s;
      }
    if (lr == 0) {
      #pragma unroll
      for (int mi = 0; mi < 4; ++mi)
        #pragma unroll
        for (int r = 0; r < 4; ++r)
          pbuf[(wave & 1) * 128 + (wave >> 1) * 64 + mi * 16 + lg * 4 + r] = part[mi][r];
    }
    __syncthreads();
    if (t < 128) psiOut[rb * 128 + t] = pbuf[t] + pbuf[t + 128] + b3c[0];
  }
}

// ---------------------------------------------------------------------------
// a2raw[j] = (psi - sy2/norm)/(lambda*ln2) + log2(nu);  block max + psi sum
__global__ void k_a2(const float* __restrict__ psi, const float* __restrict__ sy2,
                     const float* __restrict__ nu, const float* __restrict__ scal,
                     float* __restrict__ a2raw, float* __restrict__ maxp,
                     float* __restrict__ sump) {
  const int j = blockIdx.x * 256 + threadIdx.x;
  const float invn = scal[1];
  float a = -1e30f, p = 0.f;
  if (j < NP2) {
    if (j < N_REAL) {
      p = psi[j];
      a = (p - sy2[j] * invn) * (1.0f / (LAMBD * LN2)) + log2f(nu[j]);
    }
    a2raw[j] = a;
  }
  __shared__ float redm[4], reds[4];
  #pragma unroll
  for (int m = 1; m < 64; m <<= 1) {
    a = fmaxf(a, __shfl_xor(a, m, 64));
    p += __shfl_xor(p, m, 64);
  }
  const int t = threadIdx.x;
  if ((t & 63) == 0) { redm[t >> 6] = a; reds[t >> 6] = p; }
  __syncthreads();
  if (t == 0) {
    maxp[blockIdx.x] = fmaxf(fmaxf(redm[0], redm[1]), fmaxf(redm[2], redm[3]));
    sump[blockIdx.x] = reds[0] + reds[1] + reds[2] + reds[3];
  }
}

__global__ void k_fin(const float* __restrict__ maxp, const float* __restrict__ sump,
                      float* __restrict__ scal, int nb) {
  const int t = threadIdx.x;  // 128
  __shared__ float ra[2], rs[2];
  float a = -1e30f, s = 0.f;
  for (int i = t; i < nb; i += 128) { a = fmaxf(a, maxp[i]); s += sump[i]; }
  #pragma unroll
  for (int m = 1; m < 64; m <<= 1) {
    a = fmaxf(a, __shfl_xor(a, m, 64));
    s += __shfl_xor(s, m, 64);
  }
  if ((t & 63) == 0) { ra[t >> 6] = a; rs[t >> 6] = s; }
  __syncthreads();
  if (t == 0) {
    scal[3] = fmaxf(ra[0], ra[1]);                 // A2 (global max, log2 domain)
    scal[4] = (rs[0] + rs[1]) / (float)N_REAL;     // mean(psi)
  }
}

// ---------------------------------------------------------------------------
// Fused flash LSE, 256x256 tile, 8 waves (2Mx4N), BK=64, dbuf 128KB LDS.
// Minimal-sync schedule: per K-half {4x global_load_lds (next tile, same half)
// -> 12x ds_read_b128 -> setprio(1) 32 MFMA setprio(0) -> vmcnt(4) -> barrier}.
// Counted vmcnt leaves exactly this half's 4 prefetch issues in flight; the
// previous half's 4 (= next data consumed after the barrier) are forced done.
__global__ __launch_bounds__(512, 2) void k_flash(const short* __restrict__ x_t,
                                                  const short* __restrict__ y_t,
                                                  const float* __restrict__ a2raw,
                                                  const float* __restrict__ scal,
                                                  float* __restrict__ parts) {
  extern __shared__ short Lsh[];
  const int t = threadIdx.x;            // 0..511
  const int lane = t & 63, wave = t >> 6;
  const int lr = lane & 15, lg = lane >> 4;
  const int wr = wave >> 2, wc = wave & 3;
  const int rbt = blockIdx.y, split = blockIdx.x;
  const int ntiles = (NJT2 - split + NSPLIT2 - 1) / NSPLIT2;

  const float c1 = scal[2];
  const float A2 = scal[3];

  const int t8 = t * 8;                 // per-lane source offset (shorts)
  const int w512 = wave * 512;          // wave-uniform LDS offset (shorts)
  const int lg2048 = lg * 2048;
  const int aoff = (wr * 128 + lr) * 8; // + mi*128
  const int boff = (wc * 64 + lr) * 8;  // + ni*128

  const short* Abase = x_t + ((size_t)(rbt * NKT) << 14);

  f32x4 acc[8][4];
  float sums[8][4];
  #pragma unroll
  for (int mi = 0; mi < 8; ++mi)
    #pragma unroll
    for (int ni = 0; ni < 4; ++ni) {
      acc[mi][ni] = (f32x4){0.f, 0.f, 0.f, 0.f};
      sums[mi][ni] = 0.f;
    }

  auto issue = [&](int nb, const short* An, const short* Bn, int h, int op, int p) {
    const short* s = (op ? Bn : An) + h * 8192 + p * 4096 + t8;
    short* d = Lsh + (size_t)((nb * 2 + op) * 16384 + h * 8192 + p * 4096 + w512);
    gload_lds16(s, d);
  };

  // prologue: tile (i=0, kt=0) -> buf 0; age order h0:{A0,A1,B0,B1}, h1:{...}
  {
    const short* An = Abase;
    const short* Bn = y_t + ((size_t)(split * NKT) << 14);
    #pragma unroll
    for (int h = 0; h < 2; ++h)
      #pragma unroll
      for (int op = 0; op < 2; ++op)
        #pragma unroll
        for (int p = 0; p < 2; ++p)
          issue(0, An, Bn, h, op, p);
  }
  asm volatile("s_waitcnt vmcnt(4)" ::: "memory");   // h0 items done; h1 in flight
  __builtin_amdgcn_s_barrier();
  __builtin_amdgcn_sched_barrier(0);

  for (int i = 0; i < ntiles; ++i) {
    // hoist a2 loads for this jt: older than all staging issues -> forced
    // complete by the first counted vmcnt(4); no epilogue drain needed.
    const int jt = split + i * NSPLIT2;
    const float* ap = a2raw + jt * 256 + wc * 64 + lr;
    const float av0 = ap[0]  - A2;
    const float av1 = ap[16] - A2;
    const float av2 = ap[32] - A2;
    const float av3 = ap[48] - A2;

    for (int kt = 0; kt < NKT; ++kt) {
      const int buf = (i * NKT + kt) & 1;
      int in_ = i, ktn = kt + 1;
      if (ktn == NKT) { ktn = 0; ++in_; }
      const bool more = (in_ < ntiles);
      if (!more) { in_ = 0; ktn = 0; }
      const short* An = Abase + ((size_t)ktn << 14);
      const short* Bn = y_t + ((size_t)((size_t)(split + in_ * NSPLIT2) * NKT + ktn) << 14);
      const short* LA = Lsh + (size_t)((buf * 2) * 16384);
      const short* LB = Lsh + (size_t)((buf * 2 + 1) * 16384);
      const int nb = buf ^ 1;

      #pragma unroll
      for (int h = 0; h < 2; ++h) {
        const int pb = h * 8192 + lg2048;   // (h*4+lg)*256*8
        // prefetch next tile's half h (age group of 4)
        if (more) {
          issue(nb, An, Bn, h, 0, 0); issue(nb, An, Bn, h, 0, 1);
          issue(nb, An, Bn, h, 1, 0); issue(nb, An, Bn, h, 1, 1);
        }
        // fragment reads (12 x ds_read_b128)
        bf16x8 b0 = *(const bf16x8*)&LB[pb + boff];
        bf16x8 b1 = *(const bf16x8*)&LB[pb + boff + 128];
        bf16x8 b2 = *(const bf16x8*)&LB[pb + boff + 256];
        bf16x8 b3 = *(const bf16x8*)&LB[pb + boff + 384];
        bf16x8 a0 = *(const bf16x8*)&LA[pb + aoff];
        bf16x8 a1 = *(const bf16x8*)&LA[pb + aoff + 128];
        bf16x8 a2v = *(const bf16x8*)&LA[pb + aoff + 256];
        bf16x8 a3v = *(const bf16x8*)&LA[pb + aoff + 384];
        bf16x8 a4 = *(const bf16x8*)&LA[pb + aoff + 512];
        bf16x8 a5 = *(const bf16x8*)&LA[pb + aoff + 640];
        bf16x8 a6 = *(const bf16x8*)&LA[pb + aoff + 768];
        bf16x8 a7 = *(const bf16x8*)&LA[pb + aoff + 896];
        __builtin_amdgcn_s_setprio(1);
        #pragma unroll
        for (int ni = 0; ni < 4; ++ni) {
          bf16x8 bv = ni == 0 ? b0 : ni == 1 ? b1 : ni == 2 ? b2 : b3;
          acc[0][ni] = __builtin_amdgcn_mfma_f32_16x16x32_bf16(a0, bv, acc[0][ni], 0, 0, 0);
          acc[1][ni] = __builtin_amdgcn_mfma_f32_16x16x32_bf16(a1, bv, acc[1][ni], 0, 0, 0);
          acc[2][ni] = __builtin_amdgcn_mfma_f32_16x16x32_bf16(a2v, bv, acc[2][ni], 0, 0, 0);
          acc[3][ni] = __builtin_amdgcn_mfma_f32_16x16x32_bf16(a3v, bv, acc[3][ni], 0, 0, 0);
          acc[4][ni] = __builtin_amdgcn_mfma_f32_16x16x32_bf16(a4, bv, acc[4][ni], 0, 0, 0);
          acc[5][ni] = __builtin_amdgcn_mfma_f32_16x16x32_bf16(a5, bv, acc[5][ni], 0, 0, 0);
          acc[6][ni] = __builtin_amdgcn_mfma_f32_16x16x32_bf16(a6, bv, acc[6][ni], 0, 0, 0);
          acc[7][ni] = __builtin_amdgcn_mfma_f32_16x16x32_bf16(a7, bv, acc[7][ni], 0, 0, 0);
        }
        __builtin_amdgcn_s_setprio(0);
        // half boundary: counted wait (newest 4 = this half's prefetch stay in
        // flight; previous group -- the data read after this barrier -- done)
        if (more) asm volatile("s_waitcnt vmcnt(4)" ::: "memory");
        else      asm volatile("s_waitcnt vmcnt(0)" ::: "memory");
        __builtin_amdgcn_s_barrier();
        __builtin_amdgcn_sched_barrier(0);
      }
    }

    // ---- per-jt epilogue: sums += exp2(dot*c1 + a2raw[col]-A2) ----
    #pragma unroll
    for (int mi = 0; mi < 8; ++mi)
      #pragma unroll
      for (int r = 0; r < 4; ++r) {
        sums[mi][r] += exp2f(acc[mi][0][r] * c1 + av0)
                     + exp2f(acc[mi][1][r] * c1 + av1)
                     + exp2f(acc[mi][2][r] * c1 + av2)
                     + exp2f(acc[mi][3][r] * c1 + av3);
        acc[mi][0][r] = 0.f; acc[mi][1][r] = 0.f;
        acc[mi][2][r] = 0.f; acc[mi][3][r] = 0.f;
      }
  }

  // reduce each row's sum across the 16 lanes holding its columns
  #pragma unroll
  for (int mi = 0; mi < 8; ++mi)
    #pragma unroll
    for (int r = 0; r < 4; ++r) {
      float s = sums[mi][r];
      s += __shfl_xor(s, 1, 16);
      s += __shfl_xor(s, 2, 16);
      s += __shfl_xor(s, 4, 16);
      s += __shfl_xor(s, 8, 16);
      if (lr == 0) {
        const int row = rbt * 256 + wr * 128 + mi * 16 + lg * 4 + r;
        parts[(size_t)row * 64 + split * 4 + wc] = s;
      }
    }
}

// ---------------------------------------------------------------------------
__global__ void k_comb(const float* __restrict__ parts, const float* __restrict__ x2,
                       const float* __restrict__ scal, float* __restrict__ out) {
  const int b = blockIdx.x * 256 + threadIdx.x;
  if (b >= B_ROWS) return;
  float s = 0.f;
  #pragma unroll
  for (int i = 0; i < 64; ++i) s += parts[(size_t)b * 64 + i];
  out[b] = -(LAMBD * LN2) * (scal[3] + log2f(s)) + x2[b] * scal[1] + scal[4];
}

// ---------------------------------------------------------------------------
extern "C" void kernel_launch(void* const* d_in, const int* in_sizes, int n_in,
                              void* d_out, int out_size, void* d_ws, size_t ws_size,
                              hipStream_t stream) {
  const float* x  = (const float*)d_in[0];
  const float* y  = (const float*)d_in[1];
  const float* nu = (const float*)d_in[2];
  const float* W0 = (const float*)d_in[3];
  const float* b0 = (const float*)d_in[4];
  const float* W1 = (const float*)d_in[5];
  const float* b1 = (const float*)d_in[6];
  const float* W2 = (const float*)d_in[7];
  const float* b2 = (const float*)d_in[8];
  const float* W3 = (const float*)d_in[9];
  const float* b3 = (const float*)d_in[10];
  float* out = (float*)d_out;

  char* w = (char*)d_ws;
  auto alloc = [&](size_t bytes) {
    char* p = w;
    w += (bytes + 255) & ~(size_t)255;
    return p;
  };
  short* y_t   = (short*)alloc((size_t)NJT2 * NKT * 16384 * 2);           // 32.9 MB
  short* x_t   = (short*)alloc((size_t)(B_ROWS / 256) * NKT * 16384 * 2); // 6.7 MB
  short* W0b   = (short*)alloc((size_t)512 * DP2 * 2);
  short* W1b   = (short*)alloc((size_t)256 * 512 * 2);
  short* W2b   = (short*)alloc((size_t)128 * 256 * 2);
  short* H1    = (short*)alloc((size_t)NP2 * 512 * 2);
  short* H2    = (short*)alloc((size_t)NP2 * 256 * 2);
  float* sy2   = (float*)alloc((size_t)N_REAL * 4);
  float* x2    = (float*)alloc((size_t)B_ROWS * 4);
  float* psi   = (float*)alloc((size_t)NP2 * 4);
  float* a2raw = (float*)alloc((size_t)NP2 * 4);
  float* maxp  = (float*)alloc(128 * 4);
  float* sump  = (float*)alloc(128 * 4);
  float* scal  = (float*)alloc(64 * 4);
  float* parts = (float*)alloc((size_t)B_ROWS * 64 * 4);

  // fused tiled bf16 convert + exact f32 row sumsq
  k_convfuse<<<dim3(NJT2 * 4), dim3(256), 0, stream>>>(y, y_t, sy2, N_REAL);
  k_convfuse<<<dim3((B_ROWS / 256) * 4), dim3(256), 0, stream>>>(x, x_t, x2, B_ROWS);
  k_norm<<<dim3(1), dim3(1024), 0, stream>>>(sy2, scal);

  // all weights in one launch
  k_convw<<<dim3(896), dim3(256), 0, stream>>>(W0, W1, W2, W0b, W1b, W2b);

  // MLP (layer 0 reads tiled y; layer 2 fuses the final psi dot-product)
  k_gemm<true><<<dim3(4, NP2 / 128), dim3(256), 0, stream>>>(y_t, W0b, b0, H1, DP2, 512, 1,
                                                             nullptr, nullptr, nullptr);
  k_gemm<false><<<dim3(2, NP2 / 128), dim3(256), 0, stream>>>(H1, W1b, b1, H2, 512, 256, 1,
                                                              nullptr, nullptr, nullptr);
  k_gemm<false><<<dim3(1, NP2 / 128), dim3(256), 0, stream>>>(H2, W2b, b2, nullptr, 256, 128, 1,
                                                              W3, b3, psi);

  // a-vector + scalars
  const int nb_a2 = NP2 / 256;
  k_a2<<<dim3(nb_a2), dim3(256), 0, stream>>>(psi, sy2, nu, scal, a2raw, maxp, sump);
  k_fin<<<dim3(1), dim3(128), 0, stream>>>(maxp, sump, scal, nb_a2);

  // fused flash LSE (128KB dynamic LDS) + combine
  hipFuncSetAttribute((const void*)k_flash, hipFuncAttributeMaxDynamicSharedMemorySize, 131072);
  k_flash<<<dim3(NSPLIT2, B_ROWS / 256), dim3(512), 131072, stream>>>(x_t, y_t, a2raw, scal, parts);
  k_comb<<<dim3(B_ROWS / 256), dim3(256), 0, stream>>>(parts, x2, scal, out);
}

// Round 6
// 254.628 us; speedup vs baseline: 1.0499x; 1.0499x over previous
//
#include <hip/hip_runtime.h>
#include <math.h>
#include <stdint.h>
#include <stddef.h>

// Problem dims (fixed by the reference)
#define B_ROWS 4096
#define N_REAL 20000
#define NP2    20224   // N padded to 79*256
#define NJT2   79      // 256-col y tiles
#define NRT    32      // 128-row x tiles
#define D_IN   784
#define DP2    800     // K padded to 25*32
#define NKS    25      // K-steps of 32
#define LAMBD  0.05f
#define LN2    0.69314718055994530942f

typedef __attribute__((ext_vector_type(8))) short bf16x8;
typedef __attribute__((ext_vector_type(4))) float f32x4;

typedef const unsigned int __attribute__((address_space(1)))* gas_u32p;
typedef unsigned int __attribute__((address_space(3)))* las_u32p;

static __device__ __forceinline__ void gload_lds16(const short* g, short* l) {
  // dest = wave-uniform LDS base + lane*16B; source is per-lane
  __builtin_amdgcn_global_load_lds((gas_u32p)(const void*)g, (las_u32p)(void*)l, 16, 0, 0);
}

static __device__ __forceinline__ float bf2f(short s) {
  union { unsigned u; float f; } c;
  c.u = ((unsigned)(unsigned short)s) << 16;
  return c.f;
}
static __device__ __forceinline__ short f2bf(float f) {
  union { float f; unsigned u; } c;
  c.f = f;
  unsigned r = (c.u + 0x7fffu + ((c.u >> 16) & 1u)) >> 16;  // RNE
  return (short)(unsigned short)r;
}

// ---------------------------------------------------------------------------
// Fused f32->bf16 tiled convert + exact f32 row sum-of-squares.
// Image per (tile,ks): [kc=4][row=TR][8 shorts]  (TR*32 shorts).
// Block = 64-row group, 256 thr: q = col-octet (4), r = row (64).
template <int TR>
__global__ void k_convt(const float* __restrict__ src, short* __restrict__ dst,
                        float* __restrict__ rowsum, int rows_real) {
  const int g = blockIdx.x;
  const int t = threadIdx.x;
  const int q = t & 3, r = t >> 2;
  const int grow = g * 64 + r;
  const int tile = grow / TR;
  const int sub  = grow % TR;
  const float* sp = src + (size_t)grow * D_IN;
  const bool realRow = grow < rows_real;
  float sq = 0.f;

  for (int ks = 0; ks < NKS; ++ks) {
    const int c0 = ks * 32 + q * 8;
    float v[8];
    if (realRow && c0 < D_IN) {          // D_IN % 8 == 0: octet all-in or all-out
      float4 u0 = *(const float4*)(sp + c0);
      float4 u1 = *(const float4*)(sp + c0 + 4);
      v[0] = u0.x; v[1] = u0.y; v[2] = u0.z; v[3] = u0.w;
      v[4] = u1.x; v[5] = u1.y; v[6] = u1.z; v[7] = u1.w;
      sq += v[0]*v[0] + v[1]*v[1] + v[2]*v[2] + v[3]*v[3]
          + v[4]*v[4] + v[5]*v[5] + v[6]*v[6] + v[7]*v[7];
    } else {
      #pragma unroll
      for (int e = 0; e < 8; ++e) v[e] = 0.f;
    }
    bf16x8 o;
    #pragma unroll
    for (int e = 0; e < 8; ++e) o[e] = f2bf(v[e]);
    short* dp = dst + (size_t)(tile * NKS + ks) * (TR * 32)
              + ((size_t)(q * TR + sub) << 3);
    *(bf16x8*)dp = o;
  }

  sq += __shfl_xor(sq, 1, 4);
  sq += __shfl_xor(sq, 2, 4);
  if (q == 0 && realRow) rowsum[grow] = sq;
}

// ---------------------------------------------------------------------------
// All three weight converts in one launch (row-major f32 -> bf16, zero pad).
__global__ void k_convw(const float* __restrict__ W0, const float* __restrict__ W1,
                        const float* __restrict__ W2, short* __restrict__ W0b,
                        short* __restrict__ W1b, short* __restrict__ W2b) {
  const int b = blockIdx.x, t = threadIdx.x;
  const float* src; short* dst; int r, cs, cp;
  if (b < 512)      { r = b;       src = W0; dst = W0b; cs = D_IN; cp = DP2; }
  else if (b < 768) { r = b - 512; src = W1; dst = W1b; cs = 512;  cp = 512; }
  else              { r = b - 768; src = W2; dst = W2b; cs = 256;  cp = 256; }
  const float* sp = src + (size_t)r * cs;
  short* dp = dst + (size_t)r * cp;
  for (int c = t; c < cp; c += 256)
    dp[c] = f2bf(c < cs ? sp[c] : 0.f);
}

// ---------------------------------------------------------------------------
// norm = mean(sy2[0:N_REAL]); scalars: [0]=norm [1]=1/norm [2]=c1
__global__ void k_norm(const float* __restrict__ sy2, float* __restrict__ scal) {
  __shared__ float red[16];
  const int t = threadIdx.x;  // 1024
  float a = 0.f;
  for (int j = t; j < N_REAL; j += 1024) a += sy2[j];
  #pragma unroll
  for (int m = 1; m < 64; m <<= 1) a += __shfl_xor(a, m, 64);
  if ((t & 63) == 0) red[t >> 6] = a;
  __syncthreads();
  if (t == 0) {
    float s = 0.f;
    for (int i = 0; i < 16; ++i) s += red[i];
    float norm = s / (float)N_REAL;
    scal[0] = norm;
    scal[1] = 1.0f / norm;
    scal[2] = 2.0f / (norm * LAMBD * LN2);  // c1: dot -> log2 exponent
  }
}

// ---------------------------------------------------------------------------
// C[M][Ncols](bf16) = act(A * Bm^T + bias). A row-major [M][K] or TILED
// (k_convt TR=256 image layout). Bm row-major [Ncols][K]. 128x128 tile.
// If psiOut != nullptr (layer-2 mode): psi[row] = sum_col relu(v)*W3[col]+b3.
template <bool TA>
__global__ __launch_bounds__(256) void k_gemm(const short* __restrict__ A,
                                              const short* __restrict__ Bm,
                                              const float* __restrict__ bias,
                                              short* __restrict__ C,
                                              int K, int Ncols, int relu,
                                              const float* __restrict__ W3c,
                                              const float* __restrict__ b3c,
                                              float* __restrict__ psiOut) {
  __shared__ short Als[2][4096];
  __shared__ short Bls[2][4096];
  __shared__ float pbuf[256];
  const int t = threadIdx.x;
  const int lane = t & 63, wave = t >> 6;
  const int lr = lane & 15, lg = lane >> 4;
  const int wrow = (wave >> 1) * 64, wcol = (wave & 1) * 64;
  const int rb = blockIdx.y, cb = blockIdx.x;
  const int srow = t >> 2, skoff = (t & 3) * 8;
  const int KS = K >> 5;

  const short* Ag  = A + (size_t)(rb * 128 + srow) * K + skoff;
  const short* Bg  = Bm + (size_t)(cb * 128 + srow) * K + skoff;
  const size_t halfA = (size_t)64 * K;

  auto a_chunk = [&](int ks, int h) -> const short* {
    if constexpr (TA) {
      // y image: [(rb>>1)*25 + ks] of 8192 shorts; [kc=t&3][row][8]
      return A + (size_t)((rb >> 1) * NKS + ks) * 8192
               + ((size_t)((t & 3) * 256 + (rb & 1) * 128 + h * 64 + srow) << 3);
    } else {
      return Ag + ks * 32 + (h ? halfA : 0);
    }
  };

  f32x4 acc[4][4];
  #pragma unroll
  for (int mi = 0; mi < 4; ++mi)
    #pragma unroll
    for (int ni = 0; ni < 4; ++ni)
      acc[mi][ni] = (f32x4){0.f, 0.f, 0.f, 0.f};

  *(bf16x8*)&Als[0][t * 8]        = *(const bf16x8*)a_chunk(0, 0);
  *(bf16x8*)&Als[0][2048 + t * 8] = *(const bf16x8*)a_chunk(0, 1);
  *(bf16x8*)&Bls[0][t * 8]        = *(const bf16x8*)(Bg);
  *(bf16x8*)&Bls[0][2048 + t * 8] = *(const bf16x8*)(Bg + halfA);
  __syncthreads();

  int cur = 0;
  for (int ks = 0; ks < KS; ++ks) {
    bf16x8 va0, va1, vb0, vb1;
    const bool more = (ks + 1 < KS);
    if (more) {
      va0 = *(const bf16x8*)a_chunk(ks + 1, 0);
      va1 = *(const bf16x8*)a_chunk(ks + 1, 1);
      const short* Bn = Bg + (ks + 1) * 32;
      vb0 = *(const bf16x8*)(Bn);
      vb1 = *(const bf16x8*)(Bn + halfA);
    }
    bf16x8 af[4], bfr[4];
    #pragma unroll
    for (int mi = 0; mi < 4; ++mi)
      af[mi] = *(const bf16x8*)&Als[cur][(wrow + mi * 16 + lr) * 32 + lg * 8];
    #pragma unroll
    for (int ni = 0; ni < 4; ++ni)
      bfr[ni] = *(const bf16x8*)&Bls[cur][(wcol + ni * 16 + lr) * 32 + lg * 8];
    #pragma unroll
    for (int mi = 0; mi < 4; ++mi)
      #pragma unroll
      for (int ni = 0; ni < 4; ++ni)
        acc[mi][ni] = __builtin_amdgcn_mfma_f32_16x16x32_bf16(af[mi], bfr[ni], acc[mi][ni], 0, 0, 0);
    if (more) {
      const int nb = cur ^ 1;
      *(bf16x8*)&Als[nb][t * 8]        = va0;
      *(bf16x8*)&Als[nb][2048 + t * 8] = va1;
      *(bf16x8*)&Bls[nb][t * 8]        = vb0;
      *(bf16x8*)&Bls[nb][2048 + t * 8] = vb1;
    }
    __syncthreads();
    cur ^= 1;
  }

  if (psiOut == nullptr) {
    #pragma unroll
    for (int ni = 0; ni < 4; ++ni) {
      const int col = cb * 128 + wcol + ni * 16 + lr;
      const float bv = bias[col];
      #pragma unroll
      for (int mi = 0; mi < 4; ++mi) {
        const int row0 = rb * 128 + wrow + mi * 16 + lg * 4;
        #pragma unroll
        for (int r = 0; r < 4; ++r) {
          float v = acc[mi][ni][r] + bv;
          if (relu) v = fmaxf(v, 0.f);
          C[(size_t)(row0 + r) * Ncols + col] = f2bf(v);
        }
      }
    }
  } else {
    float part[4][4];
    #pragma unroll
    for (int mi = 0; mi < 4; ++mi)
      #pragma unroll
      for (int r = 0; r < 4; ++r) part[mi][r] = 0.f;
    #pragma unroll
    for (int ni = 0; ni < 4; ++ni) {
      const int col = wcol + ni * 16 + lr;
      const float bv = bias[col];
      const float w3 = W3c[col];
      #pragma unroll
      for (int mi = 0; mi < 4; ++mi)
        #pragma unroll
        for (int r = 0; r < 4; ++r)
          part[mi][r] += fmaxf(acc[mi][ni][r] + bv, 0.f) * w3;
    }
    #pragma unroll
    for (int mi = 0; mi < 4; ++mi)
      #pragma unroll
      for (int r = 0; r < 4; ++r) {
        float s = part[mi][r];
        s += __shfl_xor(s, 1, 16);
        s += __shfl_xor(s, 2, 16);
        s += __shfl_xor(s, 4, 16);
        s += __shfl_xor(s, 8, 16);
        part[mi][r] = s;
      }
    if (lr == 0) {
      #pragma unroll
      for (int mi = 0; mi < 4; ++mi)
        #pragma unroll
        for (int r = 0; r < 4; ++r)
          pbuf[(wave & 1) * 128 + (wave >> 1) * 64 + mi * 16 + lg * 4 + r] = part[mi][r];
    }
    __syncthreads();
    if (t < 128) psiOut[rb * 128 + t] = pbuf[t] + pbuf[t + 128] + b3c[0];
  }
}

// ---------------------------------------------------------------------------
// a2raw[j] = (psi - sy2/norm)/(lambda*ln2) + log2(nu);  block max + psi sum
__global__ void k_a2(const float* __restrict__ psi, const float* __restrict__ sy2,
                     const float* __restrict__ nu, const float* __restrict__ scal,
                     float* __restrict__ a2raw, float* __restrict__ maxp,
                     float* __restrict__ sump) {
  const int j = blockIdx.x * 256 + threadIdx.x;
  const float invn = scal[1];
  float a = -1e30f, p = 0.f;
  if (j < NP2) {
    if (j < N_REAL) {
      p = psi[j];
      a = (p - sy2[j] * invn) * (1.0f / (LAMBD * LN2)) + log2f(nu[j]);
    }
    a2raw[j] = a;
  }
  __shared__ float redm[4], reds[4];
  #pragma unroll
  for (int m = 1; m < 64; m <<= 1) {
    a = fmaxf(a, __shfl_xor(a, m, 64));
    p += __shfl_xor(p, m, 64);
  }
  const int t = threadIdx.x;
  if ((t & 63) == 0) { redm[t >> 6] = a; reds[t >> 6] = p; }
  __syncthreads();
  if (t == 0) {
    maxp[blockIdx.x] = fmaxf(fmaxf(redm[0], redm[1]), fmaxf(redm[2], redm[3]));
    sump[blockIdx.x] = reds[0] + reds[1] + reds[2] + reds[3];
  }
}

__global__ void k_fin(const float* __restrict__ maxp, const float* __restrict__ sump,
                      float* __restrict__ scal, int nb) {
  const int t = threadIdx.x;  // 128
  __shared__ float ra[2], rs[2];
  float a = -1e30f, s = 0.f;
  for (int i = t; i < nb; i += 128) { a = fmaxf(a, maxp[i]); s += sump[i]; }
  #pragma unroll
  for (int m = 1; m < 64; m <<= 1) {
    a = fmaxf(a, __shfl_xor(a, m, 64));
    s += __shfl_xor(s, m, 64);
  }
  if ((t & 63) == 0) { ra[t >> 6] = a; rs[t >> 6] = s; }
  __syncthreads();
  if (t == 0) {
    scal[3] = fmaxf(ra[0], ra[1]);                 // A2 (global max, log2 domain)
    scal[4] = (rs[0] + rs[1]) / (float)N_REAL;     // mean(psi)
  }
}

// ---------------------------------------------------------------------------
// Fused flash LSE: one (rbt,jt) 128x256 tile-pair per block. 8 waves of 64x64
// (2Mx4N). BK=32, TRIPLE-buffered LDS (72KB), 2-step-ahead prefetch with
// counted vmcnt(3). acc=64 regs/wave + no sums -> <=128 regs -> 16 waves/CU,
// 2 blocks/CU.
__global__ __launch_bounds__(512, 4) void k_flash(const short* __restrict__ x_t,
                                                  const short* __restrict__ y_t,
                                                  const float* __restrict__ a2raw,
                                                  const float* __restrict__ scal,
                                                  float* __restrict__ parts) {
  extern __shared__ short Lsh[];        // 3 bufs x (A 4096 + B 8192 shorts)
  const int t = threadIdx.x;            // 0..511
  const int lane = t & 63, wave = t >> 6;
  const int lr = lane & 15, lg = lane >> 4;
  const int wr = wave >> 2, wc = wave & 3;
  const int rbt = blockIdx.x, jt = blockIdx.y;

  const float c1 = scal[2];
  const float A2 = scal[3];

  const int t8 = t * 8;
  const int w512 = wave * 512;
  const int aoff = (lg * 128 + wr * 64 + lr) * 8;   // + mi*128
  const int boff = (lg * 256 + wc * 64 + lr) * 8;   // + ni*128

  const short* As = x_t + (size_t)(rbt * NKS) * 4096 + t8;   // A images 8KB
  const short* Bs = y_t + (size_t)(jt * NKS) * 8192 + t8;    // B images 16KB

  f32x4 acc[4][4];
  #pragma unroll
  for (int mi = 0; mi < 4; ++mi)
    #pragma unroll
    for (int ni = 0; ni < 4; ++ni)
      acc[mi][ni] = (f32x4){0.f, 0.f, 0.f, 0.f};

  auto stage = [&](int s) {  // 3 issues: A, B0, B1 (age-ordered)
    short* Lb = Lsh + (s % 3) * 12288;
    const short* An = As + (size_t)s * 4096;
    const short* Bn = Bs + (size_t)s * 8192;
    gload_lds16(An,        Lb + w512);
    gload_lds16(Bn,        Lb + 4096 + w512);
    gload_lds16(Bn + 4096, Lb + 8192 + w512);
  };

  // prologue: stage s0, s1; wait s0; barrier
  stage(0);
  stage(1);
  asm volatile("s_waitcnt vmcnt(3)" ::: "memory");
  __builtin_amdgcn_s_barrier();
  __builtin_amdgcn_sched_barrier(0);

  for (int ks = 0; ks < NKS; ++ks) {
    if (ks + 2 < NKS) stage(ks + 2);
    const short* LA = Lsh + (ks % 3) * 12288;
    const short* LB = LA + 4096;
    bf16x8 b0 = *(const bf16x8*)&LB[boff];
    bf16x8 b1 = *(const bf16x8*)&LB[boff + 128];
    bf16x8 b2 = *(const bf16x8*)&LB[boff + 256];
    bf16x8 b3 = *(const bf16x8*)&LB[boff + 384];
    bf16x8 a0 = *(const bf16x8*)&LA[aoff];
    bf16x8 a1 = *(const bf16x8*)&LA[aoff + 128];
    bf16x8 a2v = *(const bf16x8*)&LA[aoff + 256];
    bf16x8 a3v = *(const bf16x8*)&LA[aoff + 384];
    __builtin_amdgcn_s_setprio(1);
    #pragma unroll
    for (int ni = 0; ni < 4; ++ni) {
      bf16x8 bv = ni == 0 ? b0 : ni == 1 ? b1 : ni == 2 ? b2 : b3;
      acc[0][ni] = __builtin_amdgcn_mfma_f32_16x16x32_bf16(a0, bv, acc[0][ni], 0, 0, 0);
      acc[1][ni] = __builtin_amdgcn_mfma_f32_16x16x32_bf16(a1, bv, acc[1][ni], 0, 0, 0);
      acc[2][ni] = __builtin_amdgcn_mfma_f32_16x16x32_bf16(a2v, bv, acc[2][ni], 0, 0, 0);
      acc[3][ni] = __builtin_amdgcn_mfma_f32_16x16x32_bf16(a3v, bv, acc[3][ni], 0, 0, 0);
    }
    __builtin_amdgcn_s_setprio(0);
    // trailing boundary: protect next iter's reads (staged two iters back,
    // forced complete here) and separate reads from next iter's overwrites.
    if (ks + 2 < NKS) {
      asm volatile("s_waitcnt vmcnt(3)" ::: "memory");   // forces s_{ks+1} done
      __builtin_amdgcn_s_barrier();
      __builtin_amdgcn_sched_barrier(0);
    } else if (ks + 1 < NKS) {
      asm volatile("s_waitcnt vmcnt(0)" ::: "memory");   // forces last stage done
      __builtin_amdgcn_s_barrier();
      __builtin_amdgcn_sched_barrier(0);
    }
  }

  // epilogue: s = sum_cols exp2(dot*c1 + a2raw[col]-A2), reduce over lr lanes
  const float* ap = a2raw + jt * 256 + wc * 64 + lr;
  const float av0 = ap[0]  - A2;
  const float av1 = ap[16] - A2;
  const float av2 = ap[32] - A2;
  const float av3 = ap[48] - A2;
  #pragma unroll
  for (int mi = 0; mi < 4; ++mi)
    #pragma unroll
    for (int r = 0; r < 4; ++r) {
      float s = exp2f(acc[mi][0][r] * c1 + av0)
              + exp2f(acc[mi][1][r] * c1 + av1)
              + exp2f(acc[mi][2][r] * c1 + av2)
              + exp2f(acc[mi][3][r] * c1 + av3);
      s += __shfl_xor(s, 1, 16);
      s += __shfl_xor(s, 2, 16);
      s += __shfl_xor(s, 4, 16);
      s += __shfl_xor(s, 8, 16);
      if (lr == 0) {
        const int row = rbt * 128 + wr * 64 + mi * 16 + lg * 4 + r;
        parts[(size_t)row * (NJT2 * 4) + jt * 4 + wc] = s;
      }
    }
}

// ---------------------------------------------------------------------------
// out[b] = -lambda*ln2*(A2 + log2(sum parts[b])) + |x_b|^2/norm + mean(psi)
__global__ void k_comb(const float* __restrict__ parts, const float* __restrict__ x2,
                       const float* __restrict__ scal, float* __restrict__ out) {
  const int wave = threadIdx.x >> 6, lane = threadIdx.x & 63;
  const int row = blockIdx.x * 4 + wave;
  const float* pr = parts + (size_t)row * (NJT2 * 4);
  float s = 0.f;
  for (int i = lane; i < NJT2 * 4; i += 64) s += pr[i];
  #pragma unroll
  for (int m = 1; m < 64; m <<= 1) s += __shfl_xor(s, m, 64);
  if (lane == 0)
    out[row] = -(LAMBD * LN2) * (scal[3] + log2f(s)) + x2[row] * scal[1] + scal[4];
}

// ---------------------------------------------------------------------------
extern "C" void kernel_launch(void* const* d_in, const int* in_sizes, int n_in,
                              void* d_out, int out_size, void* d_ws, size_t ws_size,
                              hipStream_t stream) {
  const float* x  = (const float*)d_in[0];
  const float* y  = (const float*)d_in[1];
  const float* nu = (const float*)d_in[2];
  const float* W0 = (const float*)d_in[3];
  const float* b0 = (const float*)d_in[4];
  const float* W1 = (const float*)d_in[5];
  const float* b1 = (const float*)d_in[6];
  const float* W2 = (const float*)d_in[7];
  const float* b2 = (const float*)d_in[8];
  const float* W3 = (const float*)d_in[9];
  const float* b3 = (const float*)d_in[10];
  float* out = (float*)d_out;

  char* w = (char*)d_ws;
  auto alloc = [&](size_t bytes) {
    char* p = w;
    w += (bytes + 255) & ~(size_t)255;
    return p;
  };
  short* y_t   = (short*)alloc((size_t)NJT2 * NKS * 8192 * 2);   // 32.4 MB
  short* x_t   = (short*)alloc((size_t)NRT * NKS * 4096 * 2);    // 6.6 MB
  short* W0b   = (short*)alloc((size_t)512 * DP2 * 2);
  short* W1b   = (short*)alloc((size_t)256 * 512 * 2);
  short* W2b   = (short*)alloc((size_t)128 * 256 * 2);
  short* H1    = (short*)alloc((size_t)NP2 * 512 * 2);
  short* H2    = (short*)alloc((size_t)NP2 * 256 * 2);
  float* sy2   = (float*)alloc((size_t)N_REAL * 4);
  float* x2    = (float*)alloc((size_t)B_ROWS * 4);
  float* psi   = (float*)alloc((size_t)NP2 * 4);
  float* a2raw = (float*)alloc((size_t)NP2 * 4);
  float* maxp  = (float*)alloc(128 * 4);
  float* sump  = (float*)alloc(128 * 4);
  float* scal  = (float*)alloc(64 * 4);
  float* parts = (float*)alloc((size_t)B_ROWS * NJT2 * 4 * 4);   // 5.2 MB

  // fused tiled bf16 convert + exact f32 row sumsq
  k_convt<256><<<dim3(NP2 / 64), dim3(256), 0, stream>>>(y, y_t, sy2, N_REAL);
  k_convt<128><<<dim3(B_ROWS / 64), dim3(256), 0, stream>>>(x, x_t, x2, B_ROWS);
  k_norm<<<dim3(1), dim3(1024), 0, stream>>>(sy2, scal);

  // all weights in one launch (W0 padded to 800)
  k_convw<<<dim3(896), dim3(256), 0, stream>>>(W0, W1, W2, W0b, W1b, W2b);

  // MLP (layer 0 reads tiled y; layer 2 fuses the final psi dot-product)
  k_gemm<true><<<dim3(4, NP2 / 128), dim3(256), 0, stream>>>(y_t, W0b, b0, H1, DP2, 512, 1,
                                                             nullptr, nullptr, nullptr);
  k_gemm<false><<<dim3(2, NP2 / 128), dim3(256), 0, stream>>>(H1, W1b, b1, H2, 512, 256, 1,
                                                              nullptr, nullptr, nullptr);
  k_gemm<false><<<dim3(1, NP2 / 128), dim3(256), 0, stream>>>(H2, W2b, b2, nullptr, 256, 128, 1,
                                                              W3, b3, psi);

  // a-vector + scalars
  const int nb_a2 = NP2 / 256;
  k_a2<<<dim3(nb_a2), dim3(256), 0, stream>>>(psi, sy2, nu, scal, a2raw, maxp, sump);
  k_fin<<<dim3(1), dim3(128), 0, stream>>>(maxp, sump, scal, nb_a2);

  // fused flash LSE: one 128x256 tile-pair per block, 72KB triple-buffer LDS
  hipFuncSetAttribute((const void*)k_flash, hipFuncAttributeMaxDynamicSharedMemorySize, 73728);
  k_flash<<<dim3(NRT, NJT2), dim3(512), 73728, stream>>>(x_t, y_t, a2raw, scal, parts);
  k_comb<<<dim3(B_ROWS / 4), dim3(256), 0, stream>>>(parts, x2, scal, out);
}

// Round 7
// 220.101 us; speedup vs baseline: 1.2146x; 1.1569x over previous
//
#include <hip/hip_runtime.h>
#include <math.h>
#include <stdint.h>
#include <stddef.h>

// Problem dims (fixed by the reference)
#define B_ROWS 4096
#define N_REAL 20000
#define NP2    20224   // N padded to 79*256
#define NJT2   79      // 256-col y tiles
#define NRT    32      // 128-row x tiles
#define D_IN   784
#define DP2    800     // K padded to 25*32 (bf16 MLP path)
#define NKS    25      // K-steps of 32 (bf16 MLP path)
#define NKT    13      // K-tiles of 64 (i8 flash path, K padded to 832)
#define LAMBD  0.05f
#define LN2    0.69314718055994530942f

typedef __attribute__((ext_vector_type(8))) short bf16x8;
typedef __attribute__((ext_vector_type(4))) float f32x4;
typedef __attribute__((ext_vector_type(4))) int   i32x4;

typedef const unsigned int __attribute__((address_space(1)))* gas_u32p;
typedef unsigned int __attribute__((address_space(3)))* las_u32p;

static __device__ __forceinline__ void gload_lds16(const void* g, void* l) {
  // dest = wave-uniform LDS base + lane*16B; source is per-lane
  __builtin_amdgcn_global_load_lds((gas_u32p)g, (las_u32p)l, 16, 0, 0);
}

static __device__ __forceinline__ float bf2f(short s) {
  union { unsigned u; float f; } c;
  c.u = ((unsigned)(unsigned short)s) << 16;
  return c.f;
}
static __device__ __forceinline__ short f2bf(float f) {
  union { float f; unsigned u; } c;
  c.f = f;
  unsigned r = (c.u + 0x7fffu + ((c.u >> 16) & 1u)) >> 16;  // RNE
  return (short)(unsigned short)r;
}
static __device__ __forceinline__ unsigned q4(float a, float b, float c, float d, float inv) {
  int x0 = (int)rintf(a * inv) & 255;
  int x1 = (int)rintf(b * inv) & 255;
  int x2 = (int)rintf(c * inv) & 255;
  int x3 = (int)rintf(d * inv) & 255;
  return (unsigned)(x0 | (x1 << 8) | (x2 << 16) | (x3 << 24));
}

// ---------------------------------------------------------------------------
// Fused convert: per-row absmax + exact f32 sumsq (pass 1), then i8 quantize
// into tiled K-64 images [kc=4][row=TR][16B] (pass 2). Optionally also emits
// the bf16 K-32 image [oct=4][row=256][8sh] used by the MLP layer-0 GEMM.
// Block = 64 rows, 256 thr: q = 16-col chunk (4), r = row (64).
template <int TR, bool WBF>
__global__ void k_convq(const float* __restrict__ src, unsigned char* __restrict__ di8,
                        short* __restrict__ dbf, float* __restrict__ rowsum,
                        float* __restrict__ rowscale, int rows_real) {
  const int g = blockIdx.x, t = threadIdx.x;
  const int q = t & 3, r = t >> 2;
  const int grow = g * 64 + r;
  const int tile = grow / TR, sub = grow % TR;
  const float* sp = src + (size_t)grow * D_IN;
  const bool realRow = grow < rows_real;

  float amax = 0.f, sq = 0.f;
  for (int kt = 0; kt < NKT; ++kt) {
    const int c0 = kt * 64 + q * 16;
    if (realRow && c0 < D_IN) {   // D_IN % 16 == 0: chunk all-in or all-out
      #pragma unroll
      for (int u = 0; u < 4; ++u) {
        float4 v = *(const float4*)(sp + c0 + u * 4);
        sq += v.x * v.x + v.y * v.y + v.z * v.z + v.w * v.w;
        amax = fmaxf(amax, fmaxf(fmaxf(fabsf(v.x), fabsf(v.y)),
                                 fmaxf(fabsf(v.z), fabsf(v.w))));
      }
    }
  }
  sq += __shfl_xor(sq, 1, 4);  sq += __shfl_xor(sq, 2, 4);
  amax = fmaxf(amax, __shfl_xor(amax, 1, 4));
  amax = fmaxf(amax, __shfl_xor(amax, 2, 4));
  const float inv = amax > 0.f ? 127.f / amax : 0.f;
  if (q == 0) {
    if (realRow) rowsum[grow] = sq;
    rowscale[grow] = amax * (1.f / 127.f);
  }

  for (int kt = 0; kt < NKT; ++kt) {
    const int c0 = kt * 64 + q * 16;
    float v[16];
    if (realRow && c0 < D_IN) {
      #pragma unroll
      for (int u = 0; u < 4; ++u) {
        float4 w4 = *(const float4*)(sp + c0 + u * 4);
        v[u*4+0] = w4.x; v[u*4+1] = w4.y; v[u*4+2] = w4.z; v[u*4+3] = w4.w;
      }
    } else {
      #pragma unroll
      for (int e = 0; e < 16; ++e) v[e] = 0.f;
    }
    uint4 pk;
    pk.x = q4(v[0],  v[1],  v[2],  v[3],  inv);
    pk.y = q4(v[4],  v[5],  v[6],  v[7],  inv);
    pk.z = q4(v[8],  v[9],  v[10], v[11], inv);
    pk.w = q4(v[12], v[13], v[14], v[15], inv);
    *(uint4*)(di8 + (size_t)(tile * NKT + kt) * (TR * 64)
              + ((size_t)(q * TR + sub) << 4)) = pk;
    if constexpr (WBF) {
      const int ks = kt * 2 + (q >> 1);
      if (ks < NKS) {
        const int oct = (q & 1) * 2;
        short* dp = dbf + (size_t)(tile * NKS + ks) * 8192
                  + ((size_t)(oct * 256 + sub) << 3);
        bf16x8 o0, o1;
        #pragma unroll
        for (int e = 0; e < 8; ++e) { o0[e] = f2bf(v[e]); o1[e] = f2bf(v[8 + e]); }
        *(bf16x8*)dp = o0;
        *(bf16x8*)(dp + 2048) = o1;   // oct+1 plane
      }
    }
  }
}

// ---------------------------------------------------------------------------
// All three weight converts in one launch (row-major f32 -> bf16, zero pad).
__global__ void k_convw(const float* __restrict__ W0, const float* __restrict__ W1,
                        const float* __restrict__ W2, short* __restrict__ W0b,
                        short* __restrict__ W1b, short* __restrict__ W2b) {
  const int b = blockIdx.x, t = threadIdx.x;
  const float* src; short* dst; int r, cs, cp;
  if (b < 512)      { r = b;       src = W0; dst = W0b; cs = D_IN; cp = DP2; }
  else if (b < 768) { r = b - 512; src = W1; dst = W1b; cs = 512;  cp = 512; }
  else              { r = b - 768; src = W2; dst = W2b; cs = 256;  cp = 256; }
  const float* sp = src + (size_t)r * cs;
  short* dp = dst + (size_t)r * cp;
  for (int c = t; c < cp; c += 256)
    dp[c] = f2bf(c < cs ? sp[c] : 0.f);
}

// ---------------------------------------------------------------------------
// norm = mean(sy2[0:N_REAL]); scalars: [0]=norm [1]=1/norm [2]=c1
__global__ void k_norm(const float* __restrict__ sy2, float* __restrict__ scal) {
  __shared__ float red[16];
  const int t = threadIdx.x;  // 1024
  float a = 0.f;
  for (int j = t; j < N_REAL; j += 1024) a += sy2[j];
  #pragma unroll
  for (int m = 1; m < 64; m <<= 1) a += __shfl_xor(a, m, 64);
  if ((t & 63) == 0) red[t >> 6] = a;
  __syncthreads();
  if (t == 0) {
    float s = 0.f;
    for (int i = 0; i < 16; ++i) s += red[i];
    float norm = s / (float)N_REAL;
    scal[0] = norm;
    scal[1] = 1.0f / norm;
    scal[2] = 2.0f / (norm * LAMBD * LN2);  // c1: dot -> log2 exponent
  }
}

// ---------------------------------------------------------------------------
// C[M][Ncols](bf16) = act(A * Bm^T + bias). A row-major [M][K] or TILED
// (k_convq bf16 256-row image). Bm row-major [Ncols][K]. 128x128 tile.
// If psiOut != nullptr (layer-2 mode): psi[row] = sum_col relu(v)*W3[col]+b3.
template <bool TA>
__global__ __launch_bounds__(256) void k_gemm(const short* __restrict__ A,
                                              const short* __restrict__ Bm,
                                              const float* __restrict__ bias,
                                              short* __restrict__ C,
                                              int K, int Ncols, int relu,
                                              const float* __restrict__ W3c,
                                              const float* __restrict__ b3c,
                                              float* __restrict__ psiOut) {
  __shared__ short Als[2][4096];
  __shared__ short Bls[2][4096];
  __shared__ float pbuf[256];
  const int t = threadIdx.x;
  const int lane = t & 63, wave = t >> 6;
  const int lr = lane & 15, lg = lane >> 4;
  const int wrow = (wave >> 1) * 64, wcol = (wave & 1) * 64;
  const int rb = blockIdx.y, cb = blockIdx.x;
  const int srow = t >> 2, skoff = (t & 3) * 8;
  const int KS = K >> 5;

  const short* Ag  = A + (size_t)(rb * 128 + srow) * K + skoff;
  const short* Bg  = Bm + (size_t)(cb * 128 + srow) * K + skoff;
  const size_t halfA = (size_t)64 * K;

  auto a_chunk = [&](int ks, int h) -> const short* {
    if constexpr (TA) {
      // y bf16 image: [(rb>>1)*25 + ks] of 8192 shorts; [oct=t&3][row][8]
      return A + (size_t)((rb >> 1) * NKS + ks) * 8192
               + ((size_t)((t & 3) * 256 + (rb & 1) * 128 + h * 64 + srow) << 3);
    } else {
      return Ag + ks * 32 + (h ? halfA : 0);
    }
  };

  f32x4 acc[4][4];
  #pragma unroll
  for (int mi = 0; mi < 4; ++mi)
    #pragma unroll
    for (int ni = 0; ni < 4; ++ni)
      acc[mi][ni] = (f32x4){0.f, 0.f, 0.f, 0.f};

  *(bf16x8*)&Als[0][t * 8]        = *(const bf16x8*)a_chunk(0, 0);
  *(bf16x8*)&Als[0][2048 + t * 8] = *(const bf16x8*)a_chunk(0, 1);
  *(bf16x8*)&Bls[0][t * 8]        = *(const bf16x8*)(Bg);
  *(bf16x8*)&Bls[0][2048 + t * 8] = *(const bf16x8*)(Bg + halfA);
  __syncthreads();

  int cur = 0;
  for (int ks = 0; ks < KS; ++ks) {
    bf16x8 va0, va1, vb0, vb1;
    const bool more = (ks + 1 < KS);
    if (more) {
      va0 = *(const bf16x8*)a_chunk(ks + 1, 0);
      va1 = *(const bf16x8*)a_chunk(ks + 1, 1);
      const short* Bn = Bg + (ks + 1) * 32;
      vb0 = *(const bf16x8*)(Bn);
      vb1 = *(const bf16x8*)(Bn + halfA);
    }
    bf16x8 af[4], bfr[4];
    #pragma unroll
    for (int mi = 0; mi < 4; ++mi)
      af[mi] = *(const bf16x8*)&Als[cur][(wrow + mi * 16 + lr) * 32 + lg * 8];
    #pragma unroll
    for (int ni = 0; ni < 4; ++ni)
      bfr[ni] = *(const bf16x8*)&Bls[cur][(wcol + ni * 16 + lr) * 32 + lg * 8];
    #pragma unroll
    for (int mi = 0; mi < 4; ++mi)
      #pragma unroll
      for (int ni = 0; ni < 4; ++ni)
        acc[mi][ni] = __builtin_amdgcn_mfma_f32_16x16x32_bf16(af[mi], bfr[ni], acc[mi][ni], 0, 0, 0);
    if (more) {
      const int nb = cur ^ 1;
      *(bf16x8*)&Als[nb][t * 8]        = va0;
      *(bf16x8*)&Als[nb][2048 + t * 8] = va1;
      *(bf16x8*)&Bls[nb][t * 8]        = vb0;
      *(bf16x8*)&Bls[nb][2048 + t * 8] = vb1;
    }
    __syncthreads();
    cur ^= 1;
  }

  if (psiOut == nullptr) {
    #pragma unroll
    for (int ni = 0; ni < 4; ++ni) {
      const int col = cb * 128 + wcol + ni * 16 + lr;
      const float bv = bias[col];
      #pragma unroll
      for (int mi = 0; mi < 4; ++mi) {
        const int row0 = rb * 128 + wrow + mi * 16 + lg * 4;
        #pragma unroll
        for (int r = 0; r < 4; ++r) {
          float v = acc[mi][ni][r] + bv;
          if (relu) v = fmaxf(v, 0.f);
          C[(size_t)(row0 + r) * Ncols + col] = f2bf(v);
        }
      }
    }
  } else {
    float part[4][4];
    #pragma unroll
    for (int mi = 0; mi < 4; ++mi)
      #pragma unroll
      for (int r = 0; r < 4; ++r) part[mi][r] = 0.f;
    #pragma unroll
    for (int ni = 0; ni < 4; ++ni) {
      const int col = wcol + ni * 16 + lr;
      const float bv = bias[col];
      const float w3 = W3c[col];
      #pragma unroll
      for (int mi = 0; mi < 4; ++mi)
        #pragma unroll
        for (int r = 0; r < 4; ++r)
          part[mi][r] += fmaxf(acc[mi][ni][r] + bv, 0.f) * w3;
    }
    #pragma unroll
    for (int mi = 0; mi < 4; ++mi)
      #pragma unroll
      for (int r = 0; r < 4; ++r) {
        float s = part[mi][r];
        s += __shfl_xor(s, 1, 16);
        s += __shfl_xor(s, 2, 16);
        s += __shfl_xor(s, 4, 16);
        s += __shfl_xor(s, 8, 16);
        part[mi][r] = s;
      }
    if (lr == 0) {
      #pragma unroll
      for (int mi = 0; mi < 4; ++mi)
        #pragma unroll
        for (int r = 0; r < 4; ++r)
          pbuf[(wave & 1) * 128 + (wave >> 1) * 64 + mi * 16 + lg * 4 + r] = part[mi][r];
    }
    __syncthreads();
    if (t < 128) psiOut[rb * 128 + t] = pbuf[t] + pbuf[t + 128] + b3c[0];
  }
}

// ---------------------------------------------------------------------------
// a2raw[j] = (psi - sy2/norm)/(lambda*ln2) + log2(nu);  block max + psi sum
__global__ void k_a2(const float* __restrict__ psi, const float* __restrict__ sy2,
                     const float* __restrict__ nu, const float* __restrict__ scal,
                     float* __restrict__ a2raw, float* __restrict__ maxp,
                     float* __restrict__ sump) {
  const int j = blockIdx.x * 256 + threadIdx.x;
  const float invn = scal[1];
  float a = -1e30f, p = 0.f;
  if (j < NP2) {
    if (j < N_REAL) {
      p = psi[j];
      a = (p - sy2[j] * invn) * (1.0f / (LAMBD * LN2)) + log2f(nu[j]);
    }
    a2raw[j] = a;
  }
  __shared__ float redm[4], reds[4];
  #pragma unroll
  for (int m = 1; m < 64; m <<= 1) {
    a = fmaxf(a, __shfl_xor(a, m, 64));
    p += __shfl_xor(p, m, 64);
  }
  const int t = threadIdx.x;
  if ((t & 63) == 0) { redm[t >> 6] = a; reds[t >> 6] = p; }
  __syncthreads();
  if (t == 0) {
    maxp[blockIdx.x] = fmaxf(fmaxf(redm[0], redm[1]), fmaxf(redm[2], redm[3]));
    sump[blockIdx.x] = reds[0] + reds[1] + reds[2] + reds[3];
  }
}

__global__ void k_fin(const float* __restrict__ maxp, const float* __restrict__ sump,
                      float* __restrict__ scal, int nb) {
  const int t = threadIdx.x;  // 128
  __shared__ float ra[2], rs[2];
  float a = -1e30f, s = 0.f;
  for (int i = t; i < nb; i += 128) { a = fmaxf(a, maxp[i]); s += sump[i]; }
  #pragma unroll
  for (int m = 1; m < 64; m <<= 1) {
    a = fmaxf(a, __shfl_xor(a, m, 64));
    s += __shfl_xor(s, m, 64);
  }
  if ((t & 63) == 0) { ra[t >> 6] = a; rs[t >> 6] = s; }
  __syncthreads();
  if (t == 0) {
    scal[3] = fmaxf(ra[0], ra[1]);                 // A2 (global max, log2 domain)
    scal[4] = (rs[0] + rs[1]) / (float)N_REAL;     // mean(psi)
  }
}

// ---------------------------------------------------------------------------
// Fused flash LSE, INT8 MFMA (16x16x64, 2x bf16 rate, exact int32 dot).
// One (rbt,jt) 128x256 tile-pair per block; 8 waves of 64x64 (2Mx4N); BK=64;
// triple-buffered LDS (72KB), 2-ahead prefetch, counted vmcnt(3) (R6 ledger).
// dot = sx[row]*sy[col]*idot; z = idot*(sx*sy*c1) + (a2raw[col]-A2).
__global__ __launch_bounds__(512, 4) void k_flash(const unsigned char* __restrict__ x_t,
                                                  const unsigned char* __restrict__ y_t,
                                                  const float* __restrict__ a2raw,
                                                  const float* __restrict__ sxs,
                                                  const float* __restrict__ sys,
                                                  const float* __restrict__ scal,
                                                  float* __restrict__ parts) {
  extern __shared__ char Lsh[];         // 3 bufs x (A 8KB + B 16KB)
  const int t = threadIdx.x;            // 0..511
  const int lane = t & 63, wave = t >> 6;
  const int lr = lane & 15, lg = lane >> 4;
  const int wr = wave >> 2, wc = wave & 3;
  const int rbt = blockIdx.x, jt = blockIdx.y;

  const float c1 = scal[2];
  const float A2 = scal[3];

  const int t16 = t * 16;               // per-lane source offset (bytes)
  const int wb = wave * 1024;           // wave-uniform LDS offset within 8KB issue
  const int aoff = (lg * 128 + wr * 64 + lr) * 16;   // + mi*256
  const int boff = (lg * 256 + wc * 64 + lr) * 16;   // + ni*256

  const unsigned char* As = x_t + (size_t)(rbt * NKT) * 8192 + t16;   // A imgs 8KB
  const unsigned char* Bs = y_t + (size_t)(jt * NKT) * 16384 + t16;   // B imgs 16KB

  i32x4 acc[4][4];
  #pragma unroll
  for (int mi = 0; mi < 4; ++mi)
    #pragma unroll
    for (int ni = 0; ni < 4; ++ni)
      acc[mi][ni] = (i32x4){0, 0, 0, 0};

  auto stage = [&](int s) {  // 3 issues: A, B0, B1 (age-ordered)
    char* Lb = Lsh + (s % 3) * 24576;
    const unsigned char* An = As + (size_t)s * 8192;
    const unsigned char* Bn = Bs + (size_t)s * 16384;
    gload_lds16(An,        Lb + wb);
    gload_lds16(Bn,        Lb + 8192 + wb);
    gload_lds16(Bn + 8192, Lb + 16384 + wb);
  };

  // prologue: stage s0, s1; wait s0; barrier
  stage(0);
  stage(1);
  asm volatile("s_waitcnt vmcnt(3)" ::: "memory");
  __builtin_amdgcn_s_barrier();
  __builtin_amdgcn_sched_barrier(0);

  for (int ks = 0; ks < NKT; ++ks) {
    if (ks + 2 < NKT) stage(ks + 2);
    const char* LA = Lsh + (ks % 3) * 24576;
    const char* LB = LA + 8192;
    i32x4 b0 = *(const i32x4*)(LB + boff);
    i32x4 b1 = *(const i32x4*)(LB + boff + 256);
    i32x4 b2 = *(const i32x4*)(LB + boff + 512);
    i32x4 b3 = *(const i32x4*)(LB + boff + 768);
    i32x4 a0 = *(const i32x4*)(LA + aoff);
    i32x4 a1 = *(const i32x4*)(LA + aoff + 256);
    i32x4 a2v = *(const i32x4*)(LA + aoff + 512);
    i32x4 a3v = *(const i32x4*)(LA + aoff + 768);
    __builtin_amdgcn_s_setprio(1);
    #pragma unroll
    for (int ni = 0; ni < 4; ++ni) {
      i32x4 bv = ni == 0 ? b0 : ni == 1 ? b1 : ni == 2 ? b2 : b3;
      acc[0][ni] = __builtin_amdgcn_mfma_i32_16x16x64_i8(a0, bv, acc[0][ni], 0, 0, 0);
      acc[1][ni] = __builtin_amdgcn_mfma_i32_16x16x64_i8(a1, bv, acc[1][ni], 0, 0, 0);
      acc[2][ni] = __builtin_amdgcn_mfma_i32_16x16x64_i8(a2v, bv, acc[2][ni], 0, 0, 0);
      acc[3][ni] = __builtin_amdgcn_mfma_i32_16x16x64_i8(a3v, bv, acc[3][ni], 0, 0, 0);
    }
    __builtin_amdgcn_s_setprio(0);
    // trailing boundary (R6 ledger): counted wait forces the NEXT buffer's
    // stage complete; this iter's prefetch (newest 3) stays in flight.
    if (ks + 2 < NKT) {
      asm volatile("s_waitcnt vmcnt(3)" ::: "memory");
      __builtin_amdgcn_s_barrier();
      __builtin_amdgcn_sched_barrier(0);
    } else if (ks + 1 < NKT) {
      asm volatile("s_waitcnt vmcnt(0)" ::: "memory");
      __builtin_amdgcn_s_barrier();
      __builtin_amdgcn_sched_barrier(0);
    }
  }

  // epilogue: s = sum_cols exp2(idot*(sx*sy*c1) + a2raw[col]-A2)
  const int colb = jt * 256 + wc * 64 + lr;
  float av[4], syv[4];
  #pragma unroll
  for (int ni = 0; ni < 4; ++ni) {
    av[ni]  = a2raw[colb + ni * 16] - A2;
    syv[ni] = sys[colb + ni * 16];
  }
  #pragma unroll
  for (int mi = 0; mi < 4; ++mi)
    #pragma unroll
    for (int r = 0; r < 4; ++r) {
      const int row = rbt * 128 + wr * 64 + mi * 16 + lg * 4 + r;
      const float sxc = sxs[row] * c1;
      float s = exp2f((float)acc[mi][0][r] * (sxc * syv[0]) + av[0])
              + exp2f((float)acc[mi][1][r] * (sxc * syv[1]) + av[1])
              + exp2f((float)acc[mi][2][r] * (sxc * syv[2]) + av[2])
              + exp2f((float)acc[mi][3][r] * (sxc * syv[3]) + av[3]);
      s += __shfl_xor(s, 1, 16);
      s += __shfl_xor(s, 2, 16);
      s += __shfl_xor(s, 4, 16);
      s += __shfl_xor(s, 8, 16);
      if (lr == 0)
        parts[(size_t)row * (NJT2 * 4) + jt * 4 + wc] = s;
    }
}

// ---------------------------------------------------------------------------
// out[b] = -lambda*ln2*(A2 + log2(sum parts[b])) + |x_b|^2/norm + mean(psi)
__global__ void k_comb(const float* __restrict__ parts, const float* __restrict__ x2,
                       const float* __restrict__ scal, float* __restrict__ out) {
  const int wave = threadIdx.x >> 6, lane = threadIdx.x & 63;
  const int row = blockIdx.x * 4 + wave;
  const float* pr = parts + (size_t)row * (NJT2 * 4);
  float s = 0.f;
  for (int i = lane; i < NJT2 * 4; i += 64) s += pr[i];
  #pragma unroll
  for (int m = 1; m < 64; m <<= 1) s += __shfl_xor(s, m, 64);
  if (lane == 0)
    out[row] = -(LAMBD * LN2) * (scal[3] + log2f(s)) + x2[row] * scal[1] + scal[4];
}

// ---------------------------------------------------------------------------
extern "C" void kernel_launch(void* const* d_in, const int* in_sizes, int n_in,
                              void* d_out, int out_size, void* d_ws, size_t ws_size,
                              hipStream_t stream) {
  const float* x  = (const float*)d_in[0];
  const float* y  = (const float*)d_in[1];
  const float* nu = (const float*)d_in[2];
  const float* W0 = (const float*)d_in[3];
  const float* b0 = (const float*)d_in[4];
  const float* W1 = (const float*)d_in[5];
  const float* b1 = (const float*)d_in[6];
  const float* W2 = (const float*)d_in[7];
  const float* b2 = (const float*)d_in[8];
  const float* W3 = (const float*)d_in[9];
  const float* b3 = (const float*)d_in[10];
  float* out = (float*)d_out;

  char* w = (char*)d_ws;
  auto alloc = [&](size_t bytes) {
    char* p = w;
    w += (bytes + 255) & ~(size_t)255;
    return p;
  };
  unsigned char* y_i8 = (unsigned char*)alloc((size_t)NJT2 * NKT * 16384);  // 16.8 MB
  unsigned char* x_i8 = (unsigned char*)alloc((size_t)NRT * NKT * 8192);    // 3.4 MB
  short* y_bf  = (short*)alloc((size_t)(NP2 / 256) * NKS * 8192 * 2);       // 32.4 MB
  short* W0b   = (short*)alloc((size_t)512 * DP2 * 2);
  short* W1b   = (short*)alloc((size_t)256 * 512 * 2);
  short* W2b   = (short*)alloc((size_t)128 * 256 * 2);
  short* H1    = (short*)alloc((size_t)NP2 * 512 * 2);
  short* H2    = (short*)alloc((size_t)NP2 * 256 * 2);
  float* sy2   = (float*)alloc((size_t)N_REAL * 4);
  float* x2    = (float*)alloc((size_t)B_ROWS * 4);
  float* sys   = (float*)alloc((size_t)NP2 * 4);
  float* sxs   = (float*)alloc((size_t)B_ROWS * 4);
  float* psi   = (float*)alloc((size_t)NP2 * 4);
  float* a2raw = (float*)alloc((size_t)NP2 * 4);
  float* maxp  = (float*)alloc(128 * 4);
  float* sump  = (float*)alloc(128 * 4);
  float* scal  = (float*)alloc(64 * 4);
  float* parts = (float*)alloc((size_t)B_ROWS * NJT2 * 4 * 4);              // 5.2 MB

  // fused convert: absmax+sumsq, then i8 tiled images (+ bf16 image for y)
  k_convq<256, true><<<dim3(NP2 / 64), dim3(256), 0, stream>>>(y, y_i8, y_bf, sy2, sys, N_REAL);
  k_convq<128, false><<<dim3(B_ROWS / 64), dim3(256), 0, stream>>>(x, x_i8, nullptr, x2, sxs, B_ROWS);
  k_norm<<<dim3(1), dim3(1024), 0, stream>>>(sy2, scal);

  // all weights in one launch (W0 padded to 800)
  k_convw<<<dim3(896), dim3(256), 0, stream>>>(W0, W1, W2, W0b, W1b, W2b);

  // MLP bf16 (layer 0 reads tiled y; layer 2 fuses the final psi dot-product)
  k_gemm<true><<<dim3(4, NP2 / 128), dim3(256), 0, stream>>>(y_bf, W0b, b0, H1, DP2, 512, 1,
                                                             nullptr, nullptr, nullptr);
  k_gemm<false><<<dim3(2, NP2 / 128), dim3(256), 0, stream>>>(H1, W1b, b1, H2, 512, 256, 1,
                                                              nullptr, nullptr, nullptr);
  k_gemm<false><<<dim3(1, NP2 / 128), dim3(256), 0, stream>>>(H2, W2b, b2, nullptr, 256, 128, 1,
                                                              W3, b3, psi);

  // a-vector + scalars
  const int nb_a2 = NP2 / 256;
  k_a2<<<dim3(nb_a2), dim3(256), 0, stream>>>(psi, sy2, nu, scal, a2raw, maxp, sump);
  k_fin<<<dim3(1), dim3(128), 0, stream>>>(maxp, sump, scal, nb_a2);

  // fused flash LSE (int8 MFMA, 72KB triple-buffer LDS) + combine
  hipFuncSetAttribute((const void*)k_flash, hipFuncAttributeMaxDynamicSharedMemorySize, 73728);
  k_flash<<<dim3(NRT, NJT2), dim3(512), 73728, stream>>>(x_i8, y_i8, a2raw, sxs, sys, scal, parts);
  k_comb<<<dim3(B_ROWS / 4), dim3(256), 0, stream>>>(parts, x2, scal, out);
}